// Round 2
// baseline (284.896 us; speedup 1.0000x reference)
//
#include <hip/hip_runtime.h>
#include <hip/hip_bf16.h>
#include <cstdint>
#include <cstddef>

// ---------------------------------------------------------------------------
// DecoderAttention: out = ( softmax_causal( (Xe·Wq+bq)·(Xe·Wk+bk)^T / 8 ) · (Xr·Wv+bv) ) · Wo + bo
// B=8, S=1024, H=16, Dh=64, Dm=1024.  All MFMA in bf16 (16x16x32), f32 accum.
// ---------------------------------------------------------------------------

typedef __attribute__((ext_vector_type(8))) short short8;
typedef __attribute__((ext_vector_type(4))) short short4v;
typedef __attribute__((ext_vector_type(4))) float f32x4;

#define MFMA16(A, B, C) __builtin_amdgcn_mfma_f32_16x16x32_bf16(A, B, C, 0, 0, 0)

// f32 -> bf16 bits (RNE via hardware convert)
__device__ inline short f2bs(float f) {
    __bf16 h = (__bf16)f;
    return __builtin_bit_cast(short, h);
}

// ---------------------------------------------------------------------------
// GEMM: C[M,N] = A[M,K] * B[K,N] + bias[N]
//   A: f32 (A_IS_BF16=0) or bf16-bits (A_IS_BF16=1), row-major [M,K]
//   B: f32 weights addressed as  Bp[(gn>>6)*b_hs + k*b_rs + (gn&63)]  (gn global col)
//      proj (Qs/Ks/Vs [H,Dm,Dh]):  b_hs=65536, b_rs=64
//      out  (O flat [1024,1024]):  b_hs=64,    b_rs=1024
//   STORE_QKV=1: bf16 store to [B][H][S][64] layout;  =0: f32 row-major
// 128x128 tile, BK=32, 256 threads (4 waves, 2x2), 4x4 16x16 frags per wave.
// ---------------------------------------------------------------------------
template <int STORE_QKV, int A_IS_BF16>
__global__ __launch_bounds__(256, 2) void gemm_k(const void* __restrict__ Ap,
                                                 const float* __restrict__ Bp,
                                                 const float* __restrict__ bias,
                                                 void* __restrict__ Cp,
                                                 int M, int N, int K,
                                                 int b_hs, int b_rs) {
    __shared__ short As[128][40];  // [m][k], +8 pad
    __shared__ short Bs[128][40];  // [n][k], +8 pad (transposed-in-LDS weights)

    const int t = threadIdx.x;
    const int l = t & 63;
    const int w = t >> 6;
    const int wm = (w >> 1) * 64, wn = (w & 1) * 64;
    const int m0 = blockIdx.x * 128, n0 = blockIdx.y * 128;
    const int lr = l & 15, lg = l >> 4;

    f32x4 acc[4][4] = {};

    for (int k0 = 0; k0 < K; k0 += 32) {
        // ---- stage A tile [128][32] ----
        if (A_IS_BF16) {
            const short* A = (const short*)Ap;
            int r = t >> 1, c = (t & 1) * 16;
            const short8* src = (const short8*)(A + (size_t)(m0 + r) * K + k0 + c);
            short8 v0 = src[0], v1 = src[1];
            *(short8*)(&As[r][c]) = v0;
            *(short8*)(&As[r][c + 8]) = v1;
        } else {
            const float* A = (const float*)Ap;
            int r = t >> 1, c = (t & 1) * 16;
            const float* src = A + (size_t)(m0 + r) * K + k0 + c;
#pragma unroll
            for (int i = 0; i < 4; i++) {
                f32x4 v = *(const f32x4*)(src + i * 4);
                short4v b;
                b[0] = f2bs(v[0]); b[1] = f2bs(v[1]);
                b[2] = f2bs(v[2]); b[3] = f2bs(v[3]);
                *(short4v*)(&As[r][c + i * 4]) = b;
            }
        }
        // ---- stage B tile [32][128] -> Bs[n][k] (convert + transpose) ----
        {
            int kr = t >> 3;           // 0..31
            int nb = (t & 7) * 16;     // 0..112 (local col base)
#pragma unroll
            for (int i = 0; i < 4; i++) {
                int n = nb + i * 4;        // local tile col
                int gn = n0 + n;           // GLOBAL col (bug fix: was missing n0)
                const float* src = Bp + (size_t)(gn >> 6) * b_hs +
                                   (size_t)(k0 + kr) * b_rs + (gn & 63);
                f32x4 v = *(const f32x4*)src;
                Bs[n][kr]     = f2bs(v[0]);
                Bs[n + 1][kr] = f2bs(v[1]);
                Bs[n + 2][kr] = f2bs(v[2]);
                Bs[n + 3][kr] = f2bs(v[3]);
            }
        }
        __syncthreads();

        short8 af[4], bfv[4];
#pragma unroll
        for (int mi = 0; mi < 4; mi++)
            af[mi] = *(const short8*)(&As[wm + mi * 16 + lr][lg * 8]);
#pragma unroll
        for (int nj = 0; nj < 4; nj++)
            bfv[nj] = *(const short8*)(&Bs[wn + nj * 16 + lr][lg * 8]);
#pragma unroll
        for (int mi = 0; mi < 4; mi++)
#pragma unroll
            for (int nj = 0; nj < 4; nj++)
                acc[mi][nj] = MFMA16(af[mi], bfv[nj], acc[mi][nj]);
        __syncthreads();
    }

    // ---- epilogue ----
#pragma unroll
    for (int mi = 0; mi < 4; mi++) {
#pragma unroll
        for (int nj = 0; nj < 4; nj++) {
            int col = n0 + wn + nj * 16 + lr;
            float bv = bias[col];
#pragma unroll
            for (int e = 0; e < 4; e++) {
                int row = m0 + wm + mi * 16 + lg * 4 + e;
                float val = acc[mi][nj][e] + bv;
                if (STORE_QKV) {
                    int bb = row >> 10, s = row & 1023;
                    int h = col >> 6, d = col & 63;
                    ((short*)Cp)[((size_t)(bb * 16 + h) * 1024 + s) * 64 + d] = f2bs(val);
                } else {
                    ((float*)Cp)[(size_t)row * N + col] = val;
                }
            }
        }
    }
}

// ---------------------------------------------------------------------------
// Causal flash attention.
//   Q/K/V: bf16-bits [BH=128][S=1024][64]; Z out: bf16-bits [B*S][H*64]
//   Block: 256 thr (4 waves), 64 q-rows/block (16/wave), KT=64, grid (128,16).
//   scores = Q·K^T * 0.125, causal; masked lanes -> -1e30 -> exp==0 (matches
//   reference's -1e5 which underflows to 0.0f after softmax in f32).
// ---------------------------------------------------------------------------
__global__ __launch_bounds__(256, 2) void attn_k(const short* __restrict__ Q,
                                                 const short* __restrict__ Kp,
                                                 const short* __restrict__ Vp,
                                                 short* __restrict__ Z) {
    __shared__ short Ks[64][72];      // [kpos][d]
    __shared__ short Vt[64][72];      // [d][kpos] (transposed)
    __shared__ short Ps[4][16][72];   // per-wave P tile [q][kpos]

    const int t = threadIdx.x, l = t & 63, w = t >> 6;
    const int lr = l & 15, lg = l >> 4;
    const int bh = blockIdx.x, qb = blockIdx.y;
    const int q0 = qb * 64;
    const size_t base = (size_t)bh * 1024 * 64;

    short8 qf[2];
    {
        const short* qp = Q + base + (size_t)(q0 + w * 16 + lr) * 64 + lg * 8;
        qf[0] = *(const short8*)qp;
        qf[1] = *(const short8*)(qp + 32);
    }

    float mrun[4], lsum[4];
    f32x4 acc[4] = {};
#pragma unroll
    for (int e = 0; e < 4; e++) { mrun[e] = -1e30f; lsum[e] = 0.f; }

    for (int kt = 0; kt <= qb; kt++) {
        const int k0 = kt * 64;
        // ---- stage K tile (row-major) ----
        {
            const short* kp = Kp + base + (size_t)(k0 + (t >> 2)) * 64 + (t & 3) * 16;
            short8 v0 = *(const short8*)kp, v1 = *(const short8*)(kp + 8);
            *(short8*)(&Ks[t >> 2][(t & 3) * 16]) = v0;
            *(short8*)(&Ks[t >> 2][(t & 3) * 16 + 8]) = v1;
        }
        // ---- stage V tile transposed ----
        {
            const short* vp = Vp + base + (size_t)(k0 + l) * 64 + w * 16;
            short8 v0 = *(const short8*)vp, v1 = *(const short8*)(vp + 8);
#pragma unroll
            for (int j = 0; j < 8; j++) Vt[w * 16 + j][l] = v0[j];
#pragma unroll
            for (int j = 0; j < 8; j++) Vt[w * 16 + 8 + j][l] = v1[j];
        }
        __syncthreads();

        // ---- S = Q·K^T ----
        f32x4 sf[4];
#pragma unroll
        for (int n = 0; n < 4; n++) {
            f32x4 s = {};
            short8 kf0 = *(const short8*)(&Ks[n * 16 + lr][lg * 8]);
            short8 kf1 = *(const short8*)(&Ks[n * 16 + lr][lg * 8 + 32]);
            s = MFMA16(qf[0], kf0, s);
            s = MFMA16(qf[1], kf1, s);
            sf[n] = s;
        }

        // ---- online softmax (rows spread over 16-lane groups) ----
        const bool diag = (kt == qb);
        float pr[4][4];
#pragma unroll
        for (int e = 0; e < 4; e++) {
            float vals[4];
#pragma unroll
            for (int n = 0; n < 4; n++) {
                float x = sf[n][e] * 0.125f;
                if (diag && (n * 16 + lr > w * 16 + lg * 4 + e)) x = -1e30f;
                vals[n] = x;
            }
            float tm = fmaxf(fmaxf(vals[0], vals[1]), fmaxf(vals[2], vals[3]));
#pragma unroll
            for (int off = 1; off < 16; off <<= 1)
                tm = fmaxf(tm, __shfl_xor(tm, off));
            float nm = fmaxf(mrun[e], tm);
            float alpha = __expf(mrun[e] - nm);
            mrun[e] = nm;
            float rs = 0.f;
#pragma unroll
            for (int n = 0; n < 4; n++) {
                float p = __expf(vals[n] - nm);
                pr[e][n] = p;
                rs += p;
            }
#pragma unroll
            for (int off = 1; off < 16; off <<= 1)
                rs += __shfl_xor(rs, off);
            lsum[e] = lsum[e] * alpha + rs;
#pragma unroll
            for (int n4 = 0; n4 < 4; n4++) acc[n4][e] *= alpha;
        }
#pragma unroll
        for (int e = 0; e < 4; e++)
#pragma unroll
            for (int n = 0; n < 4; n++)
                Ps[w][lg * 4 + e][n * 16 + lr] = f2bs(pr[e][n]);
        __syncthreads();

        // ---- O += P·V ----
#pragma unroll
        for (int c = 0; c < 2; c++) {
            short8 pf = *(const short8*)(&Ps[w][lr][lg * 8 + c * 32]);
#pragma unroll
            for (int n4 = 0; n4 < 4; n4++) {
                short8 vf = *(const short8*)(&Vt[n4 * 16 + lr][lg * 8 + c * 32]);
                acc[n4] = MFMA16(pf, vf, acc[n4]);
            }
        }
        __syncthreads();
    }

    // ---- epilogue: Z[b*1024+q][h*64+d] = acc / lsum ----
    const int b = bh >> 4, h = bh & 15;
    float rec[4];
#pragma unroll
    for (int e = 0; e < 4; e++) rec[e] = 1.f / lsum[e];
#pragma unroll
    for (int n4 = 0; n4 < 4; n4++)
#pragma unroll
        for (int e = 0; e < 4; e++) {
            int row = q0 + w * 16 + lg * 4 + e;
            Z[((size_t)(b * 1024 + row)) * 1024 + h * 64 + n4 * 16 + lr] =
                f2bs(acc[n4][e] * rec[e]);
        }
}

// ---------------------------------------------------------------------------
extern "C" void kernel_launch(void* const* d_in, const int* in_sizes, int n_in,
                              void* d_out, int out_size, void* d_ws, size_t ws_size,
                              hipStream_t stream) {
    const float* resid = (const float*)d_in[0];  // normalized_resid_pre [8,1024,1024]
    const float* enc   = (const float*)d_in[1];  // encoder_output      [8,1024,1024]
    const float* Qs    = (const float*)d_in[2];  // [16,1024,64]
    const float* Qbs   = (const float*)d_in[3];  // [16,64]
    const float* Ksw   = (const float*)d_in[4];
    const float* Kbs   = (const float*)d_in[5];
    const float* Vs    = (const float*)d_in[6];
    const float* Vbs   = (const float*)d_in[7];
    const float* Ow    = (const float*)d_in[8];  // [16,64,1024] == [1024,1024]
    const float* Ob    = (const float*)d_in[9];  // [1024]
    float* out = (float*)d_out;

    char* ws = (char*)d_ws;
    const size_t SZ = (size_t)8 * 16 * 1024 * 64 * sizeof(short);  // 16 MiB per tensor
    short* Qw = (short*)(ws);
    short* Kw = (short*)(ws + SZ);
    short* Vw = (short*)(ws + 2 * SZ);
    short* Zw = (short*)(ws + 3 * SZ);

    dim3 gg(64, 8);
    // q,k from encoder_output; v from normalized_resid_pre
    gemm_k<1, 0><<<gg, 256, 0, stream>>>(enc,   Qs,  Qbs, Qw, 8192, 1024, 1024, 65536, 64);
    gemm_k<1, 0><<<gg, 256, 0, stream>>>(enc,   Ksw, Kbs, Kw, 8192, 1024, 1024, 65536, 64);
    gemm_k<1, 0><<<gg, 256, 0, stream>>>(resid, Vs,  Vbs, Vw, 8192, 1024, 1024, 65536, 64);
    attn_k<<<dim3(128, 16), 256, 0, stream>>>(Qw, Kw, Vw, Zw);
    gemm_k<0, 1><<<gg, 256, 0, stream>>>(Zw, Ow, Ob, out, 8192, 1024, 1024, 64, 1024);
}

// Round 3
// 177.915 us; speedup vs baseline: 1.6013x; 1.6013x over previous
//
#include <hip/hip_runtime.h>
#include <hip/hip_bf16.h>
#include <cstdint>
#include <cstddef>

// ---------------------------------------------------------------------------
// DecoderAttention on MI355X. Pipeline:
//   cvt:    enc,resid f32 -> bf16
//   wtrans: Qs/Ks/Vs/O f32 -> bf16, transposed to [n][k]
//   gemm<1>: Q = enc·Wq+bq   -> [bh][s][64] bf16
//   gemm<1>: K = enc·Wk+bk   -> [bh][s][64] bf16
//   gemm<2>: V = resid·Wv+bv -> [bh][d][s]  bf16 (transposed store)
//   attn:   causal flash, K/V staged via global_load_lds (swizzled)
//   gemm<0>: out = Z·Wo+bo   -> f32
// ---------------------------------------------------------------------------

typedef __attribute__((ext_vector_type(8))) short short8;
typedef __attribute__((ext_vector_type(4))) short short4v;
typedef __attribute__((ext_vector_type(4))) float f32x4;

#define MFMA16(A, B, C) __builtin_amdgcn_mfma_f32_16x16x32_bf16(A, B, C, 0, 0, 0)

__device__ inline short f2bs(float f) {
    __bf16 h = (__bf16)f;
    return __builtin_bit_cast(short, h);
}

typedef const __attribute__((address_space(1))) unsigned int* as1_u32p;
typedef __attribute__((address_space(3))) unsigned int* as3_u32p;

// async global->LDS, 16B/lane; LDS dest = wave-uniform base + lane*16 (m104)
__device__ inline void gload_lds16(const void* g, void* lds_base) {
    __builtin_amdgcn_global_load_lds((as1_u32p)(uintptr_t)g,
                                     (as3_u32p)(uintptr_t)lds_base, 16, 0, 0);
}

// ---------------------------------------------------------------------------
// cvt: f32 -> bf16, 8 elems/thread, grid.y selects tensor (0=enc,1=resid)
// ---------------------------------------------------------------------------
__global__ __launch_bounds__(256) void cvt_k(const float* __restrict__ a,
                                             const float* __restrict__ b,
                                             short* __restrict__ oa,
                                             short* __restrict__ ob) {
    const int n = 8 * 1024 * 1024;
    const float* src = blockIdx.y ? b : a;
    short* dst = blockIdx.y ? ob : oa;
    for (int i = (blockIdx.x * 256 + threadIdx.x) * 8; i < n; i += gridDim.x * 256 * 8) {
        f32x4 v0 = *(const f32x4*)(src + i), v1 = *(const f32x4*)(src + i + 4);
        short8 o;
        o[0] = f2bs(v0[0]); o[1] = f2bs(v0[1]); o[2] = f2bs(v0[2]); o[3] = f2bs(v0[3]);
        o[4] = f2bs(v1[0]); o[5] = f2bs(v1[1]); o[6] = f2bs(v1[2]); o[7] = f2bs(v1[3]);
        *(short8*)(dst + i) = o;
    }
}

// ---------------------------------------------------------------------------
// wtrans: weight transpose+convert.
//   wsel 0..2 (proj [16][1024][64]): T[h*64+dh][k] = W[h][k][dh]
//   wsel 3    (O    [16][64][1024]): T[d][h*64+dh] = O[h][dh][d]
// 64x64 tile per block, grid (256, 4).
// ---------------------------------------------------------------------------
__global__ __launch_bounds__(256) void wtrans_k(
    const float* __restrict__ Wq, const float* __restrict__ Wk,
    const float* __restrict__ Wv, const float* __restrict__ Wo,
    short* __restrict__ TQ, short* __restrict__ TK,
    short* __restrict__ TV, short* __restrict__ TO) {
    __shared__ short tile[64][72];
    const int wsel = blockIdx.y;
    const float* in = wsel == 0 ? Wq : wsel == 1 ? Wk : wsel == 2 ? Wv : Wo;
    short* out = wsel == 0 ? TQ : wsel == 1 ? TK : wsel == 2 ? TV : TO;
    const int h = blockIdx.x >> 4, tk = blockIdx.x & 15;
    const int t = threadIdx.x;
    size_t ioff; int istr, orow0, ocol0;
    if (wsel < 3) { ioff = (size_t)h * 65536 + (size_t)tk * 64 * 64; istr = 64;   orow0 = h * 64;  ocol0 = tk * 64; }
    else          { ioff = (size_t)h * 65536 + (size_t)tk * 64;      istr = 1024; orow0 = tk * 64; ocol0 = h * 64; }
    {
        const int r = t >> 2, c0 = (t & 3) * 16;
        const float* src = in + ioff + (size_t)r * istr + c0;
#pragma unroll
        for (int j = 0; j < 4; j++) {
            f32x4 v = *(const f32x4*)(src + j * 4);
            tile[r][c0 + j * 4 + 0] = f2bs(v[0]);
            tile[r][c0 + j * 4 + 1] = f2bs(v[1]);
            tile[r][c0 + j * 4 + 2] = f2bs(v[2]);
            tile[r][c0 + j * 4 + 3] = f2bs(v[3]);
        }
    }
    __syncthreads();
    {
        const int cc = t >> 2, rb = (t & 3) * 16;
        short8 o0, o1;
#pragma unroll
        for (int j = 0; j < 8; j++) { o0[j] = tile[rb + j][cc]; o1[j] = tile[rb + 8 + j][cc]; }
        short* dst = out + (size_t)(orow0 + cc) * 1024 + ocol0 + rb;
        *(short8*)dst = o0;
        *(short8*)(dst + 8) = o1;
    }
}

// ---------------------------------------------------------------------------
// GEMM: C[8192,1024] = A[8192,1024]·B^T + bias, A,B bf16 [row][k] row-major.
// 128x128 tile, BK=64, 4 waves (2x2), global_load_lds staging with
// involution swizzle cb^=(r&7) on global source + fragment reads (rule #21).
//   MODE 0: f32 out row-major
//   MODE 1: bf16 out [bh][s][64]   (Q, K)
//   MODE 2: bf16 out [bh][d][s]    (V, transposed, packed 8B stores)
// ---------------------------------------------------------------------------
template <int MODE>
__global__ __launch_bounds__(256) void gemm_bt(const short* __restrict__ A,
                                               const short* __restrict__ B,
                                               const float* __restrict__ bias,
                                               void* __restrict__ Cp) {
    constexpr int K = 1024;
    __shared__ short As[128 * 64];
    __shared__ short Bs[128 * 64];
    const int t = threadIdx.x, l = t & 63, w = t >> 6, lr = l & 15, lg = l >> 4;
    const int wm = (w >> 1) * 64, wn = (w & 1) * 64;
    const int m0 = blockIdx.x * 128, n0 = blockIdx.y * 128;
    const int sr = l >> 3, cb = l & 7;
    f32x4 acc[4][4] = {};

    for (int k0 = 0; k0 < K; k0 += 64) {
#pragma unroll
        for (int i = 0; i < 4; i++) {
            const int c = w * 4 + i, r = c * 8 + sr, cbs = cb ^ (r & 7);
            gload_lds16(A + (size_t)(m0 + r) * K + k0 + cbs * 8, &As[c * 512]);
        }
#pragma unroll
        for (int i = 0; i < 4; i++) {
            const int c = w * 4 + i, r = c * 8 + sr, cbs = cb ^ (r & 7);
            gload_lds16(B + (size_t)(n0 + r) * K + k0 + cbs * 8, &Bs[c * 512]);
        }
        __syncthreads();
#pragma unroll
        for (int kk = 0; kk < 2; kk++) {
            short8 af[4], bf[4];
#pragma unroll
            for (int mi = 0; mi < 4; mi++) {
                const int r = wm + mi * 16 + lr;
                af[mi] = *(const short8*)&As[r * 64 + ((kk * 4 + lg) ^ (r & 7)) * 8];
            }
#pragma unroll
            for (int nj = 0; nj < 4; nj++) {
                const int r = wn + nj * 16 + lr;
                bf[nj] = *(const short8*)&Bs[r * 64 + ((kk * 4 + lg) ^ (r & 7)) * 8];
            }
#pragma unroll
            for (int mi = 0; mi < 4; mi++)
#pragma unroll
                for (int nj = 0; nj < 4; nj++)
                    acc[mi][nj] = MFMA16(af[mi], bf[nj], acc[mi][nj]);
        }
        __syncthreads();
    }

#pragma unroll
    for (int mi = 0; mi < 4; mi++) {
#pragma unroll
        for (int nj = 0; nj < 4; nj++) {
            const int col = n0 + wn + nj * 16 + lr;
            const float bv = bias[col];
            if (MODE == 2) {
                const int rowb = m0 + wm + mi * 16 + lg * 4;
                const int bb = rowb >> 10, s0 = rowb & 1023;
                const int h = col >> 6, d = col & 63;
                short4v pk;
#pragma unroll
                for (int e = 0; e < 4; e++) pk[e] = f2bs(acc[mi][nj][e] + bv);
                *(short4v*)((short*)Cp + ((size_t)(bb * 16 + h) * 64 + d) * 1024 + s0) = pk;
            } else {
#pragma unroll
                for (int e = 0; e < 4; e++) {
                    const int row = m0 + wm + mi * 16 + lg * 4 + e;
                    const float val = acc[mi][nj][e] + bv;
                    if (MODE == 1) {
                        const int bb = row >> 10, s = row & 1023;
                        const int h = col >> 6, d = col & 63;
                        ((short*)Cp)[((size_t)(bb * 16 + h) * 1024 + s) * 64 + d] = f2bs(val);
                    } else {
                        ((float*)Cp)[(size_t)row * 1024 + col] = val;
                    }
                }
            }
        }
    }
}

// ---------------------------------------------------------------------------
// Causal flash attention.
//   Q,K: bf16 [bh][s][64]; V: bf16 [bh][d][s] (pre-transposed by gemm<2>)
//   Z out: bf16 [b*1024+s][h*64+d]
// 256 thr / 4 waves, 64 q-rows per block (16/wave), KT=64.
// K,V tiles staged with global_load_lds + involution swizzle; Ps per-wave.
// grid (128 bh, 16 qb-slots), qb reversed so heavy blocks dispatch first.
// ---------------------------------------------------------------------------
__global__ __launch_bounds__(256) void attn_k(const short* __restrict__ Q,
                                              const short* __restrict__ Kp,
                                              const short* __restrict__ Vg,
                                              short* __restrict__ Z) {
    __shared__ short Ks[64 * 64];
    __shared__ short Vt[64 * 64];
    __shared__ short Ps[4][16][72];
    const int t = threadIdx.x, l = t & 63, w = t >> 6, lr = l & 15, lg = l >> 4;
    const int bh = blockIdx.x, qb = 15 - blockIdx.y, q0 = qb * 64;
    const size_t base = (size_t)bh * 65536;
    const int sr = l >> 3, cb = l & 7;

    short8 qf[2];
    {
        const short* qp = Q + base + (size_t)(q0 + w * 16 + lr) * 64 + lg * 8;
        qf[0] = *(const short8*)qp;
        qf[1] = *(const short8*)(qp + 32);
    }

    float mrun[4], lsum[4];
    f32x4 acc[4] = {};
#pragma unroll
    for (int e = 0; e < 4; e++) { mrun[e] = -1e30f; lsum[e] = 0.f; }

    for (int kt = 0; kt <= qb; kt++) {
        const int k0 = kt * 64;
#pragma unroll
        for (int i = 0; i < 2; i++) {
            const int c = w * 2 + i, r = c * 8 + sr, cbs = cb ^ (r & 7);
            gload_lds16(Kp + base + (size_t)(k0 + r) * 64 + cbs * 8, &Ks[c * 512]);
            gload_lds16(Vg + base + (size_t)r * 1024 + k0 + cbs * 8, &Vt[c * 512]);
        }
        __syncthreads();

        // ---- S = Q·K^T ----
        f32x4 sf[4];
#pragma unroll
        for (int n = 0; n < 4; n++) {
            const int rk = n * 16 + lr;
            short8 kf0 = *(const short8*)&Ks[rk * 64 + ((lg) ^ (rk & 7)) * 8];
            short8 kf1 = *(const short8*)&Ks[rk * 64 + ((4 + lg) ^ (rk & 7)) * 8];
            f32x4 s = {};
            s = MFMA16(qf[0], kf0, s);
            s = MFMA16(qf[1], kf1, s);
            sf[n] = s;
        }

        // ---- online softmax ----
        const bool diag = (kt == qb);
        float pr[4][4];
#pragma unroll
        for (int e = 0; e < 4; e++) {
            float vals[4];
#pragma unroll
            for (int n = 0; n < 4; n++) {
                float x = sf[n][e] * 0.125f;
                if (diag && (n * 16 + lr > w * 16 + lg * 4 + e)) x = -1e30f;
                vals[n] = x;
            }
            float tm = fmaxf(fmaxf(vals[0], vals[1]), fmaxf(vals[2], vals[3]));
#pragma unroll
            for (int off = 1; off < 16; off <<= 1)
                tm = fmaxf(tm, __shfl_xor(tm, off));
            float nm = fmaxf(mrun[e], tm);
            float alpha = __expf(mrun[e] - nm);
            mrun[e] = nm;
            float rs = 0.f;
#pragma unroll
            for (int n = 0; n < 4; n++) {
                float p = __expf(vals[n] - nm);
                pr[e][n] = p;
                rs += p;
            }
#pragma unroll
            for (int off = 1; off < 16; off <<= 1)
                rs += __shfl_xor(rs, off);
            lsum[e] = lsum[e] * alpha + rs;
#pragma unroll
            for (int n4 = 0; n4 < 4; n4++) acc[n4][e] *= alpha;
        }
#pragma unroll
        for (int e = 0; e < 4; e++)
#pragma unroll
            for (int n = 0; n < 4; n++)
                Ps[w][lg * 4 + e][n * 16 + lr] = f2bs(pr[e][n]);
        // (no barrier: Ps is wave-private; compiler orders via lgkmcnt)

        // ---- O += P·V ----
#pragma unroll
        for (int c = 0; c < 2; c++) {
            short8 pf = *(const short8*)&Ps[w][lr][lg * 8 + c * 32];
#pragma unroll
            for (int n4 = 0; n4 < 4; n4++) {
                const int rv = n4 * 16 + lr;
                short8 vf = *(const short8*)&Vt[rv * 64 + ((lg + 4 * c) ^ (rv & 7)) * 8];
                acc[n4] = MFMA16(pf, vf, acc[n4]);
            }
        }
        __syncthreads();
    }

    // ---- epilogue ----
    const int b = bh >> 4, h = bh & 15;
    float rec[4];
#pragma unroll
    for (int e = 0; e < 4; e++) rec[e] = 1.f / lsum[e];
#pragma unroll
    for (int n4 = 0; n4 < 4; n4++)
#pragma unroll
        for (int e = 0; e < 4; e++) {
            const int row = q0 + w * 16 + lg * 4 + e;
            Z[((size_t)(b * 1024 + row)) * 1024 + h * 64 + n4 * 16 + lr] =
                f2bs(acc[n4][e] * rec[e]);
        }
}

// ---------------------------------------------------------------------------
extern "C" void kernel_launch(void* const* d_in, const int* in_sizes, int n_in,
                              void* d_out, int out_size, void* d_ws, size_t ws_size,
                              hipStream_t stream) {
    const float* resid = (const float*)d_in[0];
    const float* enc   = (const float*)d_in[1];
    const float* Qs    = (const float*)d_in[2];
    const float* Qbs   = (const float*)d_in[3];
    const float* Ksw   = (const float*)d_in[4];
    const float* Kbs   = (const float*)d_in[5];
    const float* Vs    = (const float*)d_in[6];
    const float* Vbs   = (const float*)d_in[7];
    const float* Ow    = (const float*)d_in[8];
    const float* Ob    = (const float*)d_in[9];
    float* out = (float*)d_out;

    char* ws = (char*)d_ws;
    const size_t M16 = (size_t)16 * 1024 * 1024;
    short* Aenc = (short*)ws;               // 16 MB; aliased as Zw after K-GEMM
    short* Ares = (short*)(ws + M16);       // 16 MB
    short* Qw   = (short*)(ws + 2 * M16);   // 16 MB
    short* Kw   = (short*)(ws + 3 * M16);   // 16 MB
    short* Vw   = (short*)(ws + 4 * M16);   // 16 MB ([bh][d][s])
    short* WqT  = (short*)(ws + 5 * M16);
    short* WkT  = (short*)(ws + 5 * M16 + 2 * 1024 * 1024);
    short* WvT  = (short*)(ws + 5 * M16 + 4 * 1024 * 1024);
    short* WoT  = (short*)(ws + 5 * M16 + 6 * 1024 * 1024);
    short* Zw   = Aenc;  // enc-bf16 dead after K-GEMM; attn runs later (stream order)

    cvt_k<<<dim3(2048, 2), 256, 0, stream>>>(enc, resid, Aenc, Ares);
    wtrans_k<<<dim3(256, 4), 256, 0, stream>>>(Qs, Ksw, Vs, Ow, WqT, WkT, WvT, WoT);
    gemm_bt<1><<<dim3(64, 8), 256, 0, stream>>>(Aenc, WqT, Qbs, Qw);
    gemm_bt<1><<<dim3(64, 8), 256, 0, stream>>>(Aenc, WkT, Kbs, Kw);
    gemm_bt<2><<<dim3(64, 8), 256, 0, stream>>>(Ares, WvT, Vbs, Vw);
    attn_k<<<dim3(128, 16), 256, 0, stream>>>(Qw, Kw, Vw, Zw);
    gemm_bt<0><<<dim3(64, 8), 256, 0, stream>>>(Zw, WoT, Ob, out);
}

// Round 4
// 163.500 us; speedup vs baseline: 1.7425x; 1.0882x over previous
//
#include <hip/hip_runtime.h>
#include <hip/hip_bf16.h>
#include <cstdint>
#include <cstddef>
#include <math.h>

// ---------------------------------------------------------------------------
// DecoderAttention on MI355X. Pipeline:
//   cvt:    enc,resid f32 -> bf16
//   wtrans: Qs/Ks/Vs/O f32 -> bf16, transposed to [n][k]
//   gemm<1>: Q = enc·Wq+bq   -> [bh][s][64] bf16
//   gemm<1>: K = enc·Wk+bk   -> [bh][s][64] bf16
//   gemm<2>: V = resid·Wv+bv -> [bh][d][s]  bf16 (transposed store)
//   attn:   causal flash, paired q-tiles {y,15-y}, defer-max softmax
//   gemm<0>: out = Z·Wo+bo   -> f32
// ---------------------------------------------------------------------------

typedef __attribute__((ext_vector_type(8))) short short8;
typedef __attribute__((ext_vector_type(4))) short short4v;
typedef __attribute__((ext_vector_type(4))) float f32x4;

#define MFMA16(A, B, C) __builtin_amdgcn_mfma_f32_16x16x32_bf16(A, B, C, 0, 0, 0)

__device__ inline short f2bs(float f) {
    __bf16 h = (__bf16)f;
    return __builtin_bit_cast(short, h);
}

typedef const __attribute__((address_space(1))) unsigned int* as1_u32p;
typedef __attribute__((address_space(3))) unsigned int* as3_u32p;

__device__ inline void gload_lds16(const void* g, void* lds_base) {
    __builtin_amdgcn_global_load_lds((as1_u32p)(uintptr_t)g,
                                     (as3_u32p)(uintptr_t)lds_base, 16, 0, 0);
}

// ---------------------------------------------------------------------------
// cvt: f32 -> bf16, 8 elems/thread, grid.y selects tensor (0=enc,1=resid)
// ---------------------------------------------------------------------------
__global__ __launch_bounds__(256) void cvt_k(const float* __restrict__ a,
                                             const float* __restrict__ b,
                                             short* __restrict__ oa,
                                             short* __restrict__ ob) {
    const int n = 8 * 1024 * 1024;
    const float* src = blockIdx.y ? b : a;
    short* dst = blockIdx.y ? ob : oa;
    for (int i = (blockIdx.x * 256 + threadIdx.x) * 8; i < n; i += gridDim.x * 256 * 8) {
        f32x4 v0 = *(const f32x4*)(src + i), v1 = *(const f32x4*)(src + i + 4);
        short8 o;
        o[0] = f2bs(v0[0]); o[1] = f2bs(v0[1]); o[2] = f2bs(v0[2]); o[3] = f2bs(v0[3]);
        o[4] = f2bs(v1[0]); o[5] = f2bs(v1[1]); o[6] = f2bs(v1[2]); o[7] = f2bs(v1[3]);
        *(short8*)(dst + i) = o;
    }
}

// ---------------------------------------------------------------------------
// wtrans: weight transpose+convert (unchanged).
// ---------------------------------------------------------------------------
__global__ __launch_bounds__(256) void wtrans_k(
    const float* __restrict__ Wq, const float* __restrict__ Wk,
    const float* __restrict__ Wv, const float* __restrict__ Wo,
    short* __restrict__ TQ, short* __restrict__ TK,
    short* __restrict__ TV, short* __restrict__ TO) {
    __shared__ short tile[64][72];
    const int wsel = blockIdx.y;
    const float* in = wsel == 0 ? Wq : wsel == 1 ? Wk : wsel == 2 ? Wv : Wo;
    short* out = wsel == 0 ? TQ : wsel == 1 ? TK : wsel == 2 ? TV : TO;
    const int h = blockIdx.x >> 4, tk = blockIdx.x & 15;
    const int t = threadIdx.x;
    size_t ioff; int istr, orow0, ocol0;
    if (wsel < 3) { ioff = (size_t)h * 65536 + (size_t)tk * 64 * 64; istr = 64;   orow0 = h * 64;  ocol0 = tk * 64; }
    else          { ioff = (size_t)h * 65536 + (size_t)tk * 64;      istr = 1024; orow0 = tk * 64; ocol0 = h * 64; }
    {
        const int r = t >> 2, c0 = (t & 3) * 16;
        const float* src = in + ioff + (size_t)r * istr + c0;
#pragma unroll
        for (int j = 0; j < 4; j++) {
            f32x4 v = *(const f32x4*)(src + j * 4);
            tile[r][c0 + j * 4 + 0] = f2bs(v[0]);
            tile[r][c0 + j * 4 + 1] = f2bs(v[1]);
            tile[r][c0 + j * 4 + 2] = f2bs(v[2]);
            tile[r][c0 + j * 4 + 3] = f2bs(v[3]);
        }
    }
    __syncthreads();
    {
        const int cc = t >> 2, rb = (t & 3) * 16;
        short8 o0, o1;
#pragma unroll
        for (int j = 0; j < 8; j++) { o0[j] = tile[rb + j][cc]; o1[j] = tile[rb + 8 + j][cc]; }
        short* dst = out + (size_t)(orow0 + cc) * 1024 + ocol0 + rb;
        *(short8*)dst = o0;
        *(short8*)(dst + 8) = o1;
    }
}

// ---------------------------------------------------------------------------
// GEMM (unchanged from round 3): 128x128, BK=64, global_load_lds + involution
// swizzle; MODE 0 f32 out, 1 bf16 [bh][s][64], 2 bf16 [bh][d][s].
// ---------------------------------------------------------------------------
template <int MODE>
__global__ __launch_bounds__(256) void gemm_bt(const short* __restrict__ A,
                                               const short* __restrict__ B,
                                               const float* __restrict__ bias,
                                               void* __restrict__ Cp) {
    constexpr int K = 1024;
    __shared__ short As[128 * 64];
    __shared__ short Bs[128 * 64];
    const int t = threadIdx.x, l = t & 63, w = t >> 6, lr = l & 15, lg = l >> 4;
    const int wm = (w >> 1) * 64, wn = (w & 1) * 64;
    const int m0 = blockIdx.x * 128, n0 = blockIdx.y * 128;
    const int sr = l >> 3, cb = l & 7;
    f32x4 acc[4][4] = {};

    for (int k0 = 0; k0 < K; k0 += 64) {
#pragma unroll
        for (int i = 0; i < 4; i++) {
            const int c = w * 4 + i, r = c * 8 + sr, cbs = cb ^ (r & 7);
            gload_lds16(A + (size_t)(m0 + r) * K + k0 + cbs * 8, &As[c * 512]);
        }
#pragma unroll
        for (int i = 0; i < 4; i++) {
            const int c = w * 4 + i, r = c * 8 + sr, cbs = cb ^ (r & 7);
            gload_lds16(B + (size_t)(n0 + r) * K + k0 + cbs * 8, &Bs[c * 512]);
        }
        __syncthreads();
#pragma unroll
        for (int kk = 0; kk < 2; kk++) {
            short8 af[4], bf[4];
#pragma unroll
            for (int mi = 0; mi < 4; mi++) {
                const int r = wm + mi * 16 + lr;
                af[mi] = *(const short8*)&As[r * 64 + ((kk * 4 + lg) ^ (r & 7)) * 8];
            }
#pragma unroll
            for (int nj = 0; nj < 4; nj++) {
                const int r = wn + nj * 16 + lr;
                bf[nj] = *(const short8*)&Bs[r * 64 + ((kk * 4 + lg) ^ (r & 7)) * 8];
            }
#pragma unroll
            for (int mi = 0; mi < 4; mi++)
#pragma unroll
                for (int nj = 0; nj < 4; nj++)
                    acc[mi][nj] = MFMA16(af[mi], bf[nj], acc[mi][nj]);
        }
        __syncthreads();
    }

#pragma unroll
    for (int mi = 0; mi < 4; mi++) {
#pragma unroll
        for (int nj = 0; nj < 4; nj++) {
            const int col = n0 + wn + nj * 16 + lr;
            const float bv = bias[col];
            if (MODE == 2) {
                const int rowb = m0 + wm + mi * 16 + lg * 4;
                const int bb = rowb >> 10, s0 = rowb & 1023;
                const int h = col >> 6, d = col & 63;
                short4v pk;
#pragma unroll
                for (int e = 0; e < 4; e++) pk[e] = f2bs(acc[mi][nj][e] + bv);
                *(short4v*)((short*)Cp + ((size_t)(bb * 16 + h) * 64 + d) * 1024 + s0) = pk;
            } else {
#pragma unroll
                for (int e = 0; e < 4; e++) {
                    const int row = m0 + wm + mi * 16 + lg * 4 + e;
                    const float val = acc[mi][nj][e] + bv;
                    if (MODE == 1) {
                        const int bb = row >> 10, s = row & 1023;
                        const int h = col >> 6, d = col & 63;
                        ((short*)Cp)[((size_t)(bb * 16 + h) * 1024 + s) * 64 + d] = f2bs(val);
                    } else {
                        ((float*)Cp)[(size_t)row * 1024 + col] = val;
                    }
                }
            }
        }
    }
}

// ---------------------------------------------------------------------------
// Causal flash attention, paired q-tiles, defer-max softmax.
//   Q,K: bf16 [bh][s][64]; V: bf16 [bh][d][s]; Z: bf16 [b*1024+s][h*64+d]
// 256 thr / 4 waves. Block y handles q-tiles qbA=y (y+1 kt) and qbB=15-y
// (16-y kt) -> uniform 17 tile-computes/block; K/V staged once per kt.
// Scores scaled by 0.125*log2e, exp2 softmax; per-lane partial sums reduced
// once in epilogue; max-reduce+rescale only when __all defer check fails.
// ---------------------------------------------------------------------------
#define ATTN_THR 11.5415603f  /* 8 * log2(e) */

__device__ __forceinline__ void attn_tile(
    const short* __restrict__ Ks, const short* __restrict__ Vt,
    short (*__restrict__ Psw)[72],
    const short8* __restrict__ qf, float* __restrict__ m,
    float* __restrict__ ps, f32x4* __restrict__ acc,
    bool diag, int lr, int lg, int rowloc) {
    // ---- S = Q·K^T (scaled, masked, in log2 units) ----
    f32x4 sf[4];
#pragma unroll
    for (int n = 0; n < 4; n++) {
        const int rk = n * 16 + lr;
        short8 kf0 = *(const short8*)&Ks[rk * 64 + ((lg) ^ (rk & 7)) * 8];
        short8 kf1 = *(const short8*)&Ks[rk * 64 + ((4 + lg) ^ (rk & 7)) * 8];
        f32x4 s = {};
        s = MFMA16(qf[0], kf0, s);
        s = MFMA16(qf[1], kf1, s);
        sf[n] = s;
    }
    const float SC = 0.18033688f;  // 0.125 * log2(e)
#pragma unroll
    for (int n = 0; n < 4; n++)
#pragma unroll
        for (int e = 0; e < 4; e++) {
            float x = sf[n][e] * SC;
            if (diag && (n * 16 + lr > rowloc + e)) x = -1e30f;
            sf[n][e] = x;
        }
    float pm[4];
#pragma unroll
    for (int e = 0; e < 4; e++)
        pm[e] = fmaxf(fmaxf(sf[0][e], sf[1][e]), fmaxf(sf[2][e], sf[3][e]));
    bool ok = true;
#pragma unroll
    for (int e = 0; e < 4; e++) ok = ok && (pm[e] <= m[e] + ATTN_THR);
    if (!__all(ok)) {
        // rare: full max-reduce + rescale
#pragma unroll
        for (int e = 0; e < 4; e++) {
            float tm = pm[e];
#pragma unroll
            for (int off = 1; off < 16; off <<= 1)
                tm = fmaxf(tm, __shfl_xor(tm, off));
            float nm = fmaxf(m[e], tm);
            float al = exp2f(m[e] - nm);
            m[e] = nm;
            ps[e] *= al;
#pragma unroll
            for (int n4 = 0; n4 < 4; n4++) acc[n4][e] *= al;
        }
    }
#pragma unroll
    for (int e = 0; e < 4; e++) {
#pragma unroll
        for (int n = 0; n < 4; n++) {
            float p = exp2f(sf[n][e] - m[e]);
            ps[e] += p;
            Psw[lg * 4 + e][n * 16 + lr] = f2bs(p);
        }
    }
    // ---- O += P·V (Ps wave-private; compiler orders via lgkmcnt) ----
#pragma unroll
    for (int c = 0; c < 2; c++) {
        short8 pf = *(const short8*)&Psw[lr][lg * 8 + c * 32];
#pragma unroll
        for (int n4 = 0; n4 < 4; n4++) {
            const int rv = n4 * 16 + lr;
            short8 vf = *(const short8*)&Vt[rv * 64 + ((lg + 4 * c) ^ (rv & 7)) * 8];
            acc[n4] = MFMA16(pf, vf, acc[n4]);
        }
    }
}

__global__ __launch_bounds__(256, 4) void attn_k(const short* __restrict__ Q,
                                                 const short* __restrict__ Kp,
                                                 const short* __restrict__ Vg,
                                                 short* __restrict__ Z) {
    __shared__ short Ks[64 * 64];
    __shared__ short Vt[64 * 64];
    __shared__ short Ps[4][16][72];
    const int t = threadIdx.x, l = t & 63, w = t >> 6, lr = l & 15, lg = l >> 4;
    const int bh = blockIdx.x;
    const int qbA = blockIdx.y, qbB = 15 - qbA;  // qbA 0..7, qbB 8..15
    const int q0A = qbA * 64, q0B = qbB * 64;
    const size_t base = (size_t)bh * 65536;
    const int sr = l >> 3, cb = l & 7;
    const int rowloc = w * 16 + lg * 4;

    short8 qfA[2], qfB[2];
    {
        const short* qp = Q + base + (size_t)(q0A + w * 16 + lr) * 64 + lg * 8;
        qfA[0] = *(const short8*)qp;
        qfA[1] = *(const short8*)(qp + 32);
        qp = Q + base + (size_t)(q0B + w * 16 + lr) * 64 + lg * 8;
        qfB[0] = *(const short8*)qp;
        qfB[1] = *(const short8*)(qp + 32);
    }

    float mA[4], mB[4], psA[4], psB[4];
    f32x4 accA[4] = {}, accB[4] = {};
#pragma unroll
    for (int e = 0; e < 4; e++) { mA[e] = mB[e] = -1e30f; psA[e] = psB[e] = 0.f; }

    for (int kt = 0; kt <= qbB; kt++) {
        const int k0 = kt * 64;
#pragma unroll
        for (int i = 0; i < 2; i++) {
            const int c = w * 2 + i, r = c * 8 + sr, cbs = cb ^ (r & 7);
            gload_lds16(Kp + base + (size_t)(k0 + r) * 64 + cbs * 8, &Ks[c * 512]);
            gload_lds16(Vg + base + (size_t)r * 1024 + k0 + cbs * 8, &Vt[c * 512]);
        }
        __syncthreads();
        if (kt <= qbA)
            attn_tile(Ks, Vt, Ps[w], qfA, mA, psA, accA, kt == qbA, lr, lg, rowloc);
        attn_tile(Ks, Vt, Ps[w], qfB, mB, psB, accB, kt == qbB, lr, lg, rowloc);
        __syncthreads();
    }

    // ---- epilogue: denom reduce (once) + normalize + store both tiles ----
    const int b = bh >> 4, h = bh & 15;
#pragma unroll
    for (int e = 0; e < 4; e++) {
        float sA = psA[e], sB = psB[e];
#pragma unroll
        for (int off = 1; off < 16; off <<= 1) {
            sA += __shfl_xor(sA, off);
            sB += __shfl_xor(sB, off);
        }
        psA[e] = 1.f / sA;
        psB[e] = 1.f / sB;
    }
#pragma unroll
    for (int n4 = 0; n4 < 4; n4++)
#pragma unroll
        for (int e = 0; e < 4; e++) {
            const int rloc = w * 16 + lg * 4 + e;
            Z[((size_t)(b * 1024 + q0A + rloc)) * 1024 + h * 64 + n4 * 16 + lr] =
                f2bs(accA[n4][e] * psA[e]);
            Z[((size_t)(b * 1024 + q0B + rloc)) * 1024 + h * 64 + n4 * 16 + lr] =
                f2bs(accB[n4][e] * psB[e]);
        }
}

// ---------------------------------------------------------------------------
extern "C" void kernel_launch(void* const* d_in, const int* in_sizes, int n_in,
                              void* d_out, int out_size, void* d_ws, size_t ws_size,
                              hipStream_t stream) {
    const float* resid = (const float*)d_in[0];
    const float* enc   = (const float*)d_in[1];
    const float* Qs    = (const float*)d_in[2];
    const float* Qbs   = (const float*)d_in[3];
    const float* Ksw   = (const float*)d_in[4];
    const float* Kbs   = (const float*)d_in[5];
    const float* Vs    = (const float*)d_in[6];
    const float* Vbs   = (const float*)d_in[7];
    const float* Ow    = (const float*)d_in[8];
    const float* Ob    = (const float*)d_in[9];
    float* out = (float*)d_out;

    char* ws = (char*)d_ws;
    const size_t M16 = (size_t)16 * 1024 * 1024;
    short* Aenc = (short*)ws;               // aliased as Zw after K-GEMM
    short* Ares = (short*)(ws + M16);
    short* Qw   = (short*)(ws + 2 * M16);
    short* Kw   = (short*)(ws + 3 * M16);
    short* Vw   = (short*)(ws + 4 * M16);   // [bh][d][s]
    short* WqT  = (short*)(ws + 5 * M16);
    short* WkT  = (short*)(ws + 5 * M16 + 2 * 1024 * 1024);
    short* WvT  = (short*)(ws + 5 * M16 + 4 * 1024 * 1024);
    short* WoT  = (short*)(ws + 5 * M16 + 6 * 1024 * 1024);
    short* Zw   = Aenc;

    cvt_k<<<dim3(2048, 2), 256, 0, stream>>>(enc, resid, Aenc, Ares);
    wtrans_k<<<dim3(256, 4), 256, 0, stream>>>(Qs, Ksw, Vs, Ow, WqT, WkT, WvT, WoT);
    gemm_bt<1><<<dim3(64, 8), 256, 0, stream>>>(Aenc, WqT, Qbs, Qw);
    gemm_bt<1><<<dim3(64, 8), 256, 0, stream>>>(Aenc, WkT, Kbs, Kw);
    gemm_bt<2><<<dim3(64, 8), 256, 0, stream>>>(Ares, WvT, Vbs, Vw);
    attn_k<<<dim3(128, 8), 256, 0, stream>>>(Qw, Kw, Vw, Zw);
    gemm_bt<0><<<dim3(64, 8), 256, 0, stream>>>(Zw, WoT, Ob, out);
}